// Round 1
// baseline (4995.993 us; speedup 1.0000x reference)
//
#include <hip/hip_runtime.h>

// WeatherLSTM: B=256, T=128, I=64, H=2048, O=24
// g = [h|x] @ Wcat + b  ;  i,f,o,c gates ; 151 sequential steps.
// Wp packed as [p][k] (col-major / B^T), p = u*4 + gate, k in [0,2112).

#define NB 256
#define NH 2048
#define NI 64
#define NK 2112      // NH + NI
#define NPK 8192     // 4*NH
#define NSTEPS 151   // 128 encoder + 23 decoder
#define NO 24

typedef __bf16 bf16x8 __attribute__((ext_vector_type(8)));
typedef short short8 __attribute__((ext_vector_type(8)));
typedef float f32x4 __attribute__((ext_vector_type(4)));
typedef unsigned short u16;

__device__ __forceinline__ u16 f2bf(float f) {
  union { float f; unsigned u; } v; v.f = f;
  unsigned r = v.u + 0x7FFFu + ((v.u >> 16) & 1u);  // RNE
  return (u16)(r >> 16);
}

__device__ __forceinline__ void gload16(const void* g, void* l) {
  __builtin_amdgcn_global_load_lds(
      (const __attribute__((address_space(1))) unsigned int*)g,
      (__attribute__((address_space(3))) unsigned int*)l, 16, 0, 0);
}

__device__ __forceinline__ float sigmoidf_(float x) {
  return 1.f / (1.f + __expf(-x));
}
__device__ __forceinline__ float tanhf_(float x) {
  x = fminf(15.f, fmaxf(-15.f, x));
  float e = __expf(2.f * x);
  return (e - 1.f) / (e + 1.f);
}

// ---- pack [Wh;Wx] fp32 [k][4H] -> Wp bf16 [p][k], p = u*4+g, via LDS transpose tile
__global__ __launch_bounds__(256) void wl_pack_w(const float* __restrict__ Wx,
                                                 const float* __restrict__ Wh,
                                                 u16* __restrict__ Wp) {
  __shared__ float s[64][65];
  const int j0 = blockIdx.x * 64, k0 = blockIdx.y * 64;
  const int tid = threadIdx.x;
  const int jl = tid & 63, kg = tid >> 6;  // kg in 0..3
#pragma unroll
  for (int it = 0; it < 16; ++it) {
    int kl = it * 4 + kg;
    int k = k0 + kl, j = j0 + jl;
    float v = (k < NH) ? Wh[(size_t)k * NPK + j] : Wx[(size_t)(k - NH) * NPK + j];
    s[kl][jl] = v;
  }
  __syncthreads();
  int j = j0 + jl;
  int p = (j & (NH - 1)) * 4 + (j >> 11);  // u*4 + gate
  short8 v0, v1;
#pragma unroll
  for (int e = 0; e < 8; ++e) {
    v0[e] = (short)f2bf(s[kg * 16 + e][jl]);
    v1[e] = (short)f2bf(s[kg * 16 + 8 + e][jl]);
  }
  short8* dst = (short8*)(Wp + (size_t)p * NK + k0 + kg * 16);
  dst[0] = v0;
  dst[1] = v1;
}

// ---- bsum[p] = bx[j] + bh[j]
__global__ __launch_bounds__(256) void wl_bsum(const float* __restrict__ bx,
                                               const float* __restrict__ bh,
                                               float* __restrict__ bsum) {
  int p = blockIdx.x * 256 + threadIdx.x;
  int j = (p & 3) * NH + (p >> 2);
  bsum[p] = bx[j] + bh[j];
}

// ---- xall[t][b][i] bf16: encoder = trains, decoder = dec*Win + b_in
__global__ __launch_bounds__(256) void wl_xall(const float* __restrict__ trains,
                                               const float* __restrict__ dec,
                                               const float* __restrict__ Win,
                                               const float* __restrict__ b_in,
                                               u16* __restrict__ xall) {
  int idx = blockIdx.x * 256 + threadIdx.x;
  int i = idx & 63;
  int b = (idx >> 6) & 255;
  int t = idx >> 14;
  float v;
  if (t < 128)
    v = trains[((size_t)b * 128 + t) * 64 + i];
  else
    v = dec[b * 23 + (t - 128)] * Win[i] + b_in[i];
  xall[idx] = f2bf(v);
}

// ---- one LSTM step: g = [h|x]@Wp + bsum ; gates ; update c,h ; y-partials
// grid 256 blocks (1/CU), 256 threads (4 waves). Tile: 64 rows x 128 packed cols,
// K loop 33 x BK=64. LDS: A/B double-buffered, XOR-swizzled (pre-swizzled source).
__global__ __launch_bounds__(256) void wl_step(const u16* __restrict__ Wp,
                                               const float* __restrict__ bsum,
                                               const u16* __restrict__ xall,
                                               u16* __restrict__ hcat,   // 2 buffers
                                               float* __restrict__ c_state,
                                               float* __restrict__ ypart,
                                               const float* __restrict__ Wout,
                                               int t) {
  __shared__ char arena[49152];  // Ab0|Ab1|Bb0|Bb1 = 8K|8K|16K|16K ; reused as gtile

  // XCD-aware mapping: xcd = flat&7 owns ub in [8*xcd, 8*xcd+8) (its Wp slice ~4.3MB)
  const int flat = blockIdx.x;
  const int q = flat >> 3;
  const int ub = (flat & 7) * 8 + (q & 7);  // 0..63 : 32 hidden units each
  const int mb = q >> 3;                    // 0..3  : 64 batch rows each
  const int b0 = mb * 64;
  const int p0 = ub * 128;
  const int u0 = ub * 32;

  const int tid = threadIdx.x;
  const int wv = tid >> 6, lane = tid & 63;
  const int l15 = lane & 15, lhi = lane >> 4;
  const int srow = lane >> 3, sc = lane & 7;  // staging: row-in-1KB-chunk, 16B chunk

  const u16* __restrict__ hin = hcat + (size_t)(t & 1) * NB * NH;
  u16* __restrict__ hout = hcat + (size_t)((t + 1) & 1) * NB * NH;

  f32x4 acc[4][2] = {};

  auto stageA = [&](int kt, int buf) {
    const u16* asrc;
    size_t astr;
    if (kt < 32) { asrc = hin + (size_t)b0 * NH + (size_t)kt * 64; astr = NH; }
    else         { asrc = xall + ((size_t)t * NB + b0) * 64;       astr = 64; }
#pragma unroll
    for (int i = 0; i < 2; ++i) {
      int qa = wv * 2 + i;              // 0..7, 1KB each
      int row = qa * 8 + srow;          // 0..63 (batch-local)
      int g8 = sc ^ (row & 7);          // pre-swizzled source chunk
      gload16(asrc + (size_t)row * astr + g8 * 8, arena + buf * 8192 + qa * 1024);
    }
  };
  auto stageB = [&](int kt, int buf) {
    const u16* bsrc = Wp + (size_t)p0 * NK + (size_t)kt * 64;
#pragma unroll
    for (int i = 0; i < 4; ++i) {
      int qb = wv * 4 + i;              // 0..15
      int col = qb * 8 + srow;          // 0..127 (packed col local)
      int g8 = sc ^ (col & 7);
      gload16(bsrc + (size_t)col * NK + g8 * 8, arena + 16384 + buf * 16384 + qb * 1024);
    }
  };

  stageA(0, 0);
  stageB(0, 0);
  for (int kt = 0; kt < 33; ++kt) {
    const int buf = kt & 1;
    if (kt < 32) {
      stageA(kt + 1, buf ^ 1);
      stageB(kt + 1, buf ^ 1);
      asm volatile("s_waitcnt vmcnt(6)" ::: "memory");  // current tile's 6 loads done
    } else {
      asm volatile("s_waitcnt vmcnt(0)" ::: "memory");
    }
    __syncthreads();
    const char* Ab = arena + buf * 8192;
    const char* Bb = arena + 16384 + buf * 16384;
#pragma unroll
    for (int kc = 0; kc < 2; ++kc) {
      bf16x8 bfr[2];
#pragma unroll
      for (int n = 0; n < 2; ++n) {
        int col = wv * 32 + n * 16 + l15;
        int c8 = kc * 4 + lhi;
        bfr[n] = *(const bf16x8*)(Bb + col * 128 + ((c8 ^ (col & 7)) << 4));
      }
#pragma unroll
      for (int m = 0; m < 4; ++m) {
        int row = m * 16 + l15;
        int c8 = kc * 4 + lhi;
        bf16x8 afr = *(const bf16x8*)(Ab + row * 128 + ((c8 ^ (row & 7)) << 4));
#pragma unroll
        for (int n = 0; n < 2; ++n)
          acc[m][n] = __builtin_amdgcn_mfma_f32_16x16x32_bf16(afr, bfr[n], acc[m][n], 0, 0, 0);
      }
    }
    __syncthreads();  // all waves done with buf before it is restaged
  }

  // spill acc -> LDS gtile[64][132] fp32 (C layout: col=lane&15, row=(lane>>4)*4+r)
  float* gtile = (float*)arena;
#pragma unroll
  for (int m = 0; m < 4; ++m)
#pragma unroll
    for (int n = 0; n < 2; ++n) {
      int row = m * 16 + lhi * 4;
      int col = wv * 32 + n * 16 + l15;
#pragma unroll
      for (int r = 0; r < 4; ++r) gtile[(row + r) * 132 + col] = acc[m][n][r];
    }
  __syncthreads();

  // gates + state update. thread: ulane = unit, bgrp covers 8 batch rows.
  const int ulane = tid & 31, bgrp = tid >> 5;
  const int ug = u0 + ulane;
  const float4 bs = *(const float4*)(bsum + p0 + ulane * 4);
  const bool emit = (t >= 127);
  const float wo = emit ? Wout[ug] : 0.f;
#pragma unroll
  for (int e = 0; e < 8; ++e) {
    int bl = bgrp + 8 * e;
    float4 g = *(const float4*)(gtile + bl * 132 + ulane * 4);
    float si = sigmoidf_(g.x + bs.x);
    float sf = sigmoidf_(g.y + bs.y);
    float so = sigmoidf_(g.z + bs.z);
    float tc = tanhf_(g.w + bs.w);
    int b = b0 + bl;
    size_t ci = (size_t)b * NH + ug;
    float cn = sf * c_state[ci] + si * tc;
    float h = so * tanhf_(cn);
    c_state[ci] = cn;
    hout[ci] = f2bf(h);
    if (emit) {
      float y = h * wo;
#pragma unroll
      for (int m = 16; m >= 1; m >>= 1) y += __shfl_xor(y, m, 64);
      if (ulane == 0) ypart[((size_t)(t - 127) * NB + b) * 64 + ub] = y;
    }
  }
}

// ---- y[b][j] = bout + sum_ub ypart[j][b][ub]
__global__ __launch_bounds__(256) void wl_finy(const float* __restrict__ ypart,
                                               const float* __restrict__ bout,
                                               float* __restrict__ out) {
  int j = blockIdx.x;
  int b = threadIdx.x;
  const float* yp = ypart + ((size_t)j * NB + b) * 64;
  float s = 0.f;
#pragma unroll
  for (int i = 0; i < 64; ++i) s += yp[i];
  out[b * NO + j] = s + bout[0];
}

extern "C" void kernel_launch(void* const* d_in, const int* in_sizes, int n_in,
                              void* d_out, int out_size, void* d_ws, size_t ws_size,
                              hipStream_t stream) {
  const float* trains = (const float*)d_in[0];
  const float* dec    = (const float*)d_in[1];
  const float* Wx     = (const float*)d_in[2];
  const float* bx     = (const float*)d_in[3];
  const float* Wh     = (const float*)d_in[4];
  const float* bh     = (const float*)d_in[5];
  const float* Win    = (const float*)d_in[6];
  const float* b_in   = (const float*)d_in[7];
  const float* Wout   = (const float*)d_in[8];
  const float* bout   = (const float*)d_in[9];
  float* out = (float*)d_out;
  char* ws = (char*)d_ws;

  u16*   Wp      = (u16*)(ws);                    // 34,603,008 B
  float* bsum    = (float*)(ws + 34603008);       //     32,768 B
  u16*   xall    = (u16*)(ws + 34635776);         //  4,947,968 B
  u16*   hcat    = (u16*)(ws + 39583744);         //  2,097,152 B (double-buffered h)
  float* c_state = (float*)(ws + 41680896);       //  2,097,152 B
  float* ypart   = (float*)(ws + 43778048);       //  1,572,864 B   total ~45.4 MB

  // zero h (both buffers) + c
  hipMemsetAsync(ws + 39583744, 0, 4194304, stream);
  wl_pack_w<<<dim3(128, 33), 256, 0, stream>>>(Wx, Wh, Wp);
  wl_bsum<<<32, 256, 0, stream>>>(bx, bh, bsum);
  wl_xall<<<(NSTEPS * NB * NI) / 256, 256, 0, stream>>>(trains, dec, Win, b_in, xall);
  for (int t = 0; t < NSTEPS; ++t)
    wl_step<<<256, 256, 0, stream>>>(Wp, bsum, xall, hcat, c_state, ypart, Wout, t);
  wl_finy<<<NO, 256, 0, stream>>>(ypart, bout, out);
}